// Round 7
// baseline (290.841 us; speedup 1.0000x reference)
//
#include <hip/hip_runtime.h>
#include <hip/hip_bf16.h>
#include <stdint.h>

typedef unsigned short u16;
typedef __bf16 v8bf __attribute__((ext_vector_type(8)));
typedef float f32x4 __attribute__((ext_vector_type(4)));

#define BATCH 2
#define NSEQ  2048
#define DIM_  2048
#define QH    16
#define KVH   4
#define HD    128
#define KVDIM 512
#define QKVS  3072
#define MROWS (BATCH*NSEQ)

__device__ __forceinline__ u16 f2bf(float f) {
  uint32_t u = __builtin_bit_cast(uint32_t, f);
  u += 0x7FFFu + ((u >> 16) & 1u);
  return (u16)(u >> 16);
}
__device__ __forceinline__ float bf2f(u16 h) {
  uint32_t u = ((uint32_t)h) << 16;
  return __builtin_bit_cast(float, u);
}
__device__ __forceinline__ uint32_t cvt_pk_bf16(float lo, float hi) {
  uint32_t r;
  asm("v_cvt_pk_bf16_f32 %0, %1, %2" : "=v"(r) : "v"(lo), "v"(hi));
  return r;
}
__device__ __forceinline__ void gload_lds16(const void* g, void* l) {
  __builtin_amdgcn_global_load_lds((const __attribute__((address_space(1))) void*)g,
                                   (__attribute__((address_space(3))) void*)l, 16, 0, 0);
}

// ---------------- fused weight converts ----------------
__global__ void k_conv_w(const float* __restrict__ wq, const float* __restrict__ wk,
                         const float* __restrict__ wv, const float* __restrict__ wo,
                         u16* __restrict__ oq, u16* __restrict__ ok,
                         u16* __restrict__ ov, u16* __restrict__ oo) {
  int i = (blockIdx.x * 256 + threadIdx.x) * 4;
  const float* in; u16* out; int e;
  if (i < 4194304)      { in = wq; out = oq; e = i; }
  else if (i < 5242880) { in = wk; out = ok; e = i - 4194304; }
  else if (i < 6291456) { in = wv; out = ov; e = i - 5242880; }
  else                  { in = wo; out = oo; e = i - 6291456; }
  float4 v = *(const float4*)(in + e);
  ushort4 o;
  o.x = f2bf(v.x); o.y = f2bf(v.y); o.z = f2bf(v.z); o.w = f2bf(v.w);
  *(ushort4*)(out + e) = o;
}

// ---------------- fused activation converts ----------------
__global__ void k_conv_x(const float* __restrict__ q, const float* __restrict__ k,
                         const float* __restrict__ v,
                         u16* __restrict__ oq, u16* __restrict__ ok, u16* __restrict__ ov) {
  int i = (blockIdx.x * 256 + threadIdx.x) * 4;
  int r = i >> 23;
  int e = i & ((1 << 23) - 1);
  const float* in = (r == 0) ? q : (r == 1 ? k : v);
  u16* out = (r == 0) ? oq : (r == 1 ? ok : ov);
  float4 vv = *(const float4*)(in + e);
  ushort4 o;
  o.x = f2bf(vv.x); o.y = f2bf(vv.y); o.z = f2bf(vv.z); o.w = f2bf(vv.w);
  *(ushort4*)(out + e) = o;
}

// ---------------- RoPE cos/sin table: [NSEQ][64] float2 ----------------
__global__ void k_rope_table2(float2* __restrict__ tab) {
  int idx = blockIdx.x * 256 + threadIdx.x;
  if (idx < NSEQ * 64) {
    int i = idx & 63;
    float inv = powf(10000.0f, -(float)i / 64.0f);
    float ang = (float)(idx >> 6) * inv;
    tab[idx] = make_float2(cosf(ang), sinf(ang));
  }
}

// ---------------- V transpose ----------------
__global__ void k_transpose_v(const u16* __restrict__ vp, u16* __restrict__ vt) {
  size_t idx = (size_t)blockIdx.x * 256 + threadIdx.x;
  if (idx >= (size_t)BATCH * KVH * HD * NSEQ) return;
  int n = (int)(idx & (NSEQ - 1));
  int d = (int)((idx >> 11) & (HD - 1));
  int h = (int)((idx >> 18) & (KVH - 1));
  int b = (int)(idx >> 20);
  vt[idx] = vp[(size_t)(b * NSEQ + n) * QKVS + h * HD + d];
}

// ============ 256x256 8-phase GEMM machinery (BK=64, 8 waves 2Mx4N) ============
// LDS: [buf][half 128-rows][row][64 K] x (A,B) = 128 KiB. XOR swizzle cb^=(row&7)<<4
// applied: linear gload_lds dest + inverse-swizzled global src + swizzled ds_read.
// Stage schedule (iter i computes tiles t0=2i buf0 @p1-4, t1 buf1 @p5-8):
//   p1: t1.A.q1  p2: t1.B.h0  p3: t1.B.h1 + (t0+2).A.q0  p4: WAIT vmcnt(2|0)
//   p5: (t0+2).A.q1  p6: (t0+2).B.h0  p7: (t0+2).B.h1  p8: (t0+3).A.q0 + WAIT vmcnt(2)
// Every staged region's last read is in a strictly earlier phase (quarter-granular).

#define STG_A(T, QM)                                                              \
  { _Pragma("unroll") for (int h_ = 0; h_ < 2; ++h_) {                            \
      int r_ = l >> 3;                                                            \
      const char* s_ = Ab + (size_t)(grow0 + h_ * 128 + (QM) * 64 + w * 8 + r_) * 4096 \
                       + (size_t)(T) * 128 + (((l & 7) ^ r_) << 4);               \
      gload_lds16(s_, (char*)&Als[(T) & 1][h_][(QM) * 64 + w * 8][0]);            \
    } }

#define STG_B(T, H)                                                               \
  { _Pragma("unroll") for (int q_ = 0; q_ < 2; ++q_) {                            \
      int r_ = l >> 3;                                                            \
      const char* s_ = Bb + (size_t)(gcol0l + (H) * 128 + q_ * 64 + w * 8 + r_) * 4096 \
                       + (size_t)(T) * 128 + (((l & 7) ^ r_) << 4);               \
      gload_lds16(s_, (char*)&Bls[(T) & 1][H][q_ * 64 + w * 8][0]);               \
    } }

#define WAIT2 asm volatile("s_waitcnt vmcnt(2)" ::: "memory");
#define WAIT0 asm volatile("s_waitcnt vmcnt(0)" ::: "memory");
#define WAIT8 asm volatile("s_waitcnt vmcnt(8)" ::: "memory");

#define PH(BUF, QM, QN, STAGE, WAITCODE)                                          \
  {                                                                               \
    v8bf af_[4][2], bf_[2][2];                                                    \
    _Pragma("unroll") for (int mi = 0; mi < 4; ++mi)                              \
      _Pragma("unroll") for (int ks = 0; ks < 2; ++ks)                            \
        af_[mi][ks] = *(const v8bf*)((const char*)&Als[BUF][wr][0][0] +           \
            ((QM) * 64 + mi * 16 + lr) * 128 +                                    \
            ((ks * 64 + lg * 16) ^ ((lr & 7) << 4)));                             \
    _Pragma("unroll") for (int ni = 0; ni < 2; ++ni)                              \
      _Pragma("unroll") for (int ks = 0; ks < 2; ++ks)                            \
        bf_[ni][ks] = *(const v8bf*)((const char*)&Bls[BUF][wc >> 1][0][0] +      \
            (((wc & 1) * 64 + (QN) * 32 + ni * 16 + lr)) * 128 +                  \
            ((ks * 64 + lg * 16) ^ ((lr & 7) << 4)));                             \
    STAGE                                                                         \
    __builtin_amdgcn_s_barrier();                                                 \
    asm volatile("s_waitcnt lgkmcnt(0)" ::: "memory");                            \
    __builtin_amdgcn_sched_barrier(0);                                            \
    __builtin_amdgcn_s_setprio(1);                                                \
    _Pragma("unroll") for (int mi = 0; mi < 4; ++mi)                              \
      _Pragma("unroll") for (int ni = 0; ni < 2; ++ni)                            \
        _Pragma("unroll") for (int ks = 0; ks < 2; ++ks)                          \
          acc[(QM) * 4 + mi][(QN) * 2 + ni] = __builtin_amdgcn_mfma_f32_16x16x32_bf16( \
              af_[mi][ks], bf_[ni][ks], acc[(QM) * 4 + mi][(QN) * 2 + ni], 0, 0, 0); \
    __builtin_amdgcn_s_setprio(0);                                                \
    WAITCODE                                                                      \
    __builtin_amdgcn_s_barrier();                                                 \
  }

#define GEMM8_LOOP                                                                \
  f32x4 acc[8][4] = {};                                                           \
  STG_A(0, 0) STG_A(0, 1) STG_B(0, 0) STG_B(0, 1)                                 \
  STG_A(1, 0) STG_A(1, 1) STG_B(1, 0) STG_B(1, 1)                                 \
  WAIT8                                                                           \
  __builtin_amdgcn_s_barrier();                                                   \
  for (int i = 0; i < 16; ++i) {                                                  \
    int t0 = 2 * i, t1 = 2 * i + 1;                                               \
    bool nl = (i < 15);                                                           \
    PH(0, 0, 0, { if (i) STG_A(t1, 1) }, {})                                      \
    PH(0, 0, 1, { if (i) STG_B(t1, 0) }, {})                                      \
    PH(0, 1, 0, { if (i) STG_B(t1, 1) if (nl) STG_A(t0 + 2, 0) }, {})             \
    PH(0, 1, 1, {}, { if (nl) { WAIT2 } else { WAIT0 } })                         \
    PH(1, 0, 0, { if (nl) STG_A(t0 + 2, 1) }, {})                                 \
    PH(1, 0, 1, { if (nl) STG_B(t0 + 2, 0) }, {})                                 \
    PH(1, 1, 0, { if (nl) STG_B(t0 + 2, 1) }, {})                                 \
    PH(1, 1, 1, { if (nl) STG_A(t0 + 3, 0) }, { if (nl) WAIT2 })                  \
  }

// ---------- fused QKV GEMM, 8-phase 256^2: C(4096,3072) + RoPE epilogue ----------
__global__ __launch_bounds__(512, 2) void k_gemm_qkv8(
    const u16* __restrict__ xq, const u16* __restrict__ xk, const u16* __restrict__ xv,
    const u16* __restrict__ wq, const u16* __restrict__ wk, const u16* __restrict__ wv,
    const float* __restrict__ bq, const float* __restrict__ bk, const float* __restrict__ bv,
    const float2* __restrict__ tab2, u16* __restrict__ C) {
  __shared__ __align__(16) u16 Als[2][2][128][64];
  __shared__ __align__(16) u16 Bls[2][2][128][64];
  int tid = threadIdx.x;
  int l = tid & 63, w = tid >> 6;
  int lg = l >> 4, lr = l & 15;
  int wr = w >> 2, wc = w & 3;

  int bid = blockIdx.x;                 // 192 blocks
  int swz = (bid & 7) * 24 + (bid >> 3);
  int bm = swz & 15, bn = swz >> 4;     // bm 0..15, bn 0..11

  const u16* A; const u16* Bw; const float* bias; int bnl;
  if (bn < 8)       { A = xq; Bw = wq; bnl = bn;      bias = bq; }
  else if (bn < 10) { A = xk; Bw = wk; bnl = bn - 8;  bias = bk; }
  else              { A = xv; Bw = wv; bnl = bn - 10; bias = bv; }
  int grow0 = bm * 256;
  int gcol0l = bnl * 256;
  const char* Ab = (const char*)A;
  const char* Bb = (const char*)Bw;

  GEMM8_LOOP

  bool rope = (bn < 10);
#pragma unroll
  for (int fm = 0; fm < 8; ++fm)
#pragma unroll
    for (int fn = 0; fn < 4; ++fn) {
      int grow = bm * 256 + wr * 128 + fm * 16 + lg * 4;
      int lcol = bnl * 256 + wc * 64 + fn * 16 + lr;
      int gcol = bn * 256 + wc * 64 + fn * 16 + lr;
      float bsv = bias[lcol];
      if (rope) {
        int i2 = (gcol & 127) >> 1;
#pragma unroll
        for (int r = 0; r < 4; ++r) {
          float v = acc[fm][fn][r] + bsv;
          float pv = __shfl_xor(v, 1);
          int t = (grow + r) & (NSEQ - 1);
          float2 cs = tab2[t * 64 + i2];
          float y = (lr & 1) ? (pv * cs.y + v * cs.x) : (v * cs.x - pv * cs.y);
          C[(size_t)(grow + r) * QKVS + gcol] = f2bf(y);
        }
      } else {
#pragma unroll
        for (int r = 0; r < 4; ++r)
          C[(size_t)(grow + r) * QKVS + gcol] = f2bf(acc[fm][fn][r] + bsv);
      }
    }
}

// ---------- output GEMM, 8-phase 256^2: C(4096,2048) fp32 = A @ Wo^T + bo ----------
__global__ __launch_bounds__(512, 2) void k_gemm_bt8(const u16* __restrict__ Ain,
                                                     const u16* __restrict__ Bw,
                                                     const float* __restrict__ bias,
                                                     float* __restrict__ C) {
  __shared__ __align__(16) u16 Als[2][2][128][64];
  __shared__ __align__(16) u16 Bls[2][2][128][64];
  int tid = threadIdx.x;
  int l = tid & 63, w = tid >> 6;
  int lg = l >> 4, lr = l & 15;
  int wr = w >> 2, wc = w & 3;

  int bid = blockIdx.x;                 // 128 blocks
  int swz = (bid & 7) * 16 + (bid >> 3);
  int bm = swz & 15, bn = swz >> 4;     // bm 0..15, bn 0..7

  int grow0 = bm * 256;
  int gcol0l = bn * 256;
  const char* Ab = (const char*)Ain;
  const char* Bb = (const char*)Bw;

  GEMM8_LOOP

#pragma unroll
  for (int fm = 0; fm < 8; ++fm)
#pragma unroll
    for (int fn = 0; fn < 4; ++fn) {
      int grow = bm * 256 + wr * 128 + fm * 16 + lg * 4;
      int gcol = bn * 256 + wc * 64 + fn * 16 + lr;
      float bsv = bias[gcol];
#pragma unroll
      for (int r = 0; r < 4; ++r)
        C[(size_t)(grow + r) * DIM_ + gcol] = acc[fm][fn][r] + bsv;
    }
}

// ---------------- flash attention v3 (unchanged, verified) ----------------
__global__ __launch_bounds__(256, 2) void k_attn(const u16* __restrict__ q, const u16* __restrict__ k,
                                                 const u16* __restrict__ vt, u16* __restrict__ out) {
  __shared__ __align__(16) u16 Ks[64 * 128];
  __shared__ __align__(16) u16 Vs[128 * 64];

  int tid = threadIdx.x;
  int l = tid & 63, w = tid >> 6;
  int lg = l >> 4, lr = l & 15;
  int h = blockIdx.y, b = blockIdx.z;
  int kvh = h >> 2;
  const float SCL2 = 0.12752551286084109f;
  const float THR2 = 11.541560327111708f;

  const char* kbase = (const char*)k + ((size_t)(b * NSEQ) * QKVS + kvh * HD) * 2;
  const char* vbase = (const char*)vt + ((size_t)(b * KVH + kvh) * HD) * NSEQ * 2;
  char* KsB = (char*)Ks;
  char* VsB = (char*)Vs;

  int krow0 = tid >> 4;
  int kcol = (tid & 15) * 16;
  int vrow0 = tid >> 3;
  int vcol = (tid & 7) * 16;

  v8bf kr[4], vr[4];

#define LOADKV(KT)                                                                          \
  {                                                                                         \
    _Pragma("unroll") for (int i = 0; i < 4; ++i)                                           \
        kr[i] = *(const v8bf*)(kbase + (size_t)((KT) * 64 + krow0 + i * 16) * QKVS * 2 + kcol); \
    _Pragma("unroll") for (int i = 0; i < 4; ++i)                                           \
        vr[i] = *(const v8bf*)(vbase + (size_t)(vrow0 + i * 32) * NSEQ * 2 + (size_t)(KT) * 128 + vcol); \
  }
#define WRITEKV()                                                                           \
  {                                                                                         \
    _Pragma("unroll") for (int i = 0; i < 4; ++i) {                                         \
      int kvl = krow0 + i * 16;                                                             \
      int prow = (kvl & 32) + ((kvl & 4) << 2) + ((kvl & 24) >> 1) + (kvl & 3);             \
      *(v8bf*)(KsB + prow * 256 + (kcol ^ ((prow & 7) << 4))) = kr[i];                      \
    }                                                                                       \
    _Pragma("unroll") for (int i = 0; i < 4; ++i) {                                         \
      int row = vrow0 + i * 32;                                                             \
      *(v8bf*)(VsB + row * 128 + (vcol ^ ((row & 7) << 4))) = vr[i];                        \
    }                                                                                       \
  }

  for (int pass = 0; pass < 2; ++pass) {
    int qt = pass ? (31 - blockIdx.x) : blockIdx.x;
    int q0 = qt * 64 + w * 16;

    const char* qb = (const char*)q + ((size_t)(b * NSEQ + q0 + lr) * QKVS + h * HD) * 2;
    v8bf qf[4];
#pragma unroll
    for (int kk = 0; kk < 4; ++kk) qf[kk] = *(const v8bf*)(qb + kk * 64 + lg * 16);

    f32x4 od[8] = {};
    float m2 = -INFINITY, lsum = 0.f;
    int qrow = q0 + lr;

    int ktmax = qt;
    LOADKV(0);
    WRITEKV();
    __syncthreads();

    for (int kt = 0; kt <= ktmax; ++kt) {
      if (kt < ktmax) LOADKV(kt + 1);

      f32x4 st[4];
      __builtin_amdgcn_s_setprio(1);
#pragma unroll
      for (int nt = 0; nt < 4; ++nt) {
        f32x4 a = {};
#pragma unroll
        for (int kk = 0; kk < 4; ++kk) {
          int krow = nt * 16 + lr;
          v8bf kf = *(const v8bf*)(KsB + krow * 256 + ((kk * 64 + lg * 16) ^ ((krow & 7) << 4)));
          a = __builtin_amdgcn_mfma_f32_16x16x32_bf16(kf, qf[kk], a, 0, 0, 0);
        }
        st[nt] = a;
      }
      __builtin_amdgcn_s_setprio(0);

      float mx = -1e30f;
#pragma unroll
      for (int nt = 0; nt < 4; ++nt)
#pragma unroll
        for (int r = 0; r < 4; ++r) {
          int kv = kt * 64 + (nt >> 1) * 32 + lg * 8 + ((nt & 1) << 2) + r;
          float v = st[nt][r] * SCL2;
          if (kv > qrow) v = -1e30f;
          st[nt][r] = v;
          mx = fmaxf(mx, v);
        }
      mx = fmaxf(mx, __shfl_xor(mx, 16));
      mx = fmaxf(mx, __shfl_xor(mx, 32));

      if (!__all(mx - m2 <= THR2)) {
        float nm2 = fmaxf(m2, mx);
        float corrf = exp2f(m2 - nm2);
        m2 = nm2;
        lsum *= corrf;
#pragma unroll
        for (int r = 0; r < 4; ++r) {
          float cb = __shfl(corrf, lg * 4 + r);
#pragma unroll
          for (int dt = 0; dt < 8; ++dt) od[dt][r] *= cb;
        }
      }

      float rs = 0.f;
#pragma unroll
      for (int nt = 0; nt < 4; ++nt)
#pragma unroll
        for (int r = 0; r < 4; ++r) {
          float pv = exp2f(st[nt][r] - m2);
          st[nt][r] = pv;
          rs += pv;
        }
      rs += __shfl_xor(rs, 16);
      rs += __shfl_xor(rs, 32);
      lsum += rs;

      uint32_t pk[4][2];
#pragma unroll
      for (int nt = 0; nt < 4; ++nt)
#pragma unroll
        for (int s = 0; s < 2; ++s)
          pk[nt][s] = cvt_pk_bf16(st[nt][2 * s], st[nt][2 * s + 1]);

      __builtin_amdgcn_s_setprio(1);
#pragma unroll
      for (int kc = 0; kc < 2; ++kc) {
        union { uint32_t u[4]; v8bf v; } pfu;
        pfu.u[0] = pk[2 * kc][0];
        pfu.u[1] = pk[2 * kc][1];
        pfu.u[2] = pk[2 * kc + 1][0];
        pfu.u[3] = pk[2 * kc + 1][1];
#pragma unroll
        for (int dt = 0; dt < 8; ++dt) {
          int vrow = dt * 16 + lr;
          v8bf vf = *(const v8bf*)(VsB + vrow * 128 + ((kc * 64 + lg * 16) ^ ((vrow & 7) << 4)));
          od[dt] = __builtin_amdgcn_mfma_f32_16x16x32_bf16(pfu.v, vf, od[dt], 0, 0, 0);
        }
      }
      __builtin_amdgcn_s_setprio(0);

      __syncthreads();
      if (kt < ktmax) WRITEKV();
      __syncthreads();
    }

#pragma unroll
    for (int r = 0; r < 4; ++r) {
      float ls = __shfl(lsum, lg * 4 + r);
      float inv = 1.0f / ls;
      int qr = q0 + lg * 4 + r;
      char* ob = (char*)out + ((size_t)(b * NSEQ + qr) * DIM_ + h * HD) * 2;
#pragma unroll
      for (int dt = 0; dt < 8; ++dt)
        *(u16*)(ob + (dt * 16 + lr) * 2) = f2bf(od[dt][r] * inv);
    }
  }
#undef LOADKV
#undef WRITEKV
}

// ---------------- launch ----------------
extern "C" void kernel_launch(void* const* d_in, const int* in_sizes, int n_in,
                              void* d_out, int out_size, void* d_ws, size_t ws_size,
                              hipStream_t stream) {
  const float* query = (const float*)d_in[0];
  const float* key_ = (const float*)d_in[1];
  const float* value = (const float*)d_in[2];
  const float* Wq = (const float*)d_in[3];
  const float* bq = (const float*)d_in[4];
  const float* Wk = (const float*)d_in[5];
  const float* bk = (const float*)d_in[6];
  const float* Wv = (const float*)d_in[7];
  const float* bv = (const float*)d_in[8];
  const float* Wo = (const float*)d_in[9];
  const float* bo = (const float*)d_in[10];

  char* ws = (char*)d_ws;
  u16* wq_bf = (u16*)(ws + 0);
  u16* wk_bf = (u16*)(ws + 8388608);
  u16* wv_bf = (u16*)(ws + 10485760);
  u16* wo_bf = (u16*)(ws + 12582912);
  float2* tab2 = (float2*)(ws + 20971520);
  u16* xq = (u16*)(ws + 22020096);
  u16* xk = (u16*)(ws + 38797312);
  u16* xv = (u16*)(ws + 55574528);
  u16* qkvproj = (u16*)(ws + 72351744);
  u16* vt = xq;       // xq dead after fused QKV GEMM
  u16* attno = xk;    // xk dead after fused QKV GEMM

  k_conv_w<<<dim3(10240), 256, 0, stream>>>(Wq, Wk, Wv, Wo, wq_bf, wk_bf, wv_bf, wo_bf);
  k_conv_x<<<dim3(24576), 256, 0, stream>>>(query, key_, value, xq, xk, xv);
  k_rope_table2<<<dim3(NSEQ * 64 / 256), 256, 0, stream>>>(tab2);

  k_gemm_qkv8<<<dim3(192), 512, 0, stream>>>(xq, xk, xv, wq_bf, wk_bf, wv_bf,
                                             bq, bk, bv, tab2, qkvproj);

  k_transpose_v<<<dim3((BATCH * KVH * HD * NSEQ) / 256), 256, 0, stream>>>(qkvproj + 2560, vt);

  k_attn<<<dim3(NSEQ / 128, QH, BATCH), 256, 0, stream>>>(qkvproj, qkvproj + 2048, vt, attno);

  k_gemm_bt8<<<dim3(128), 512, 0, stream>>>(attno, wo_bf, bo, (float*)d_out);
}

// Round 8
// 227.684 us; speedup vs baseline: 1.2774x; 1.2774x over previous
//
#include <hip/hip_runtime.h>
#include <hip/hip_bf16.h>
#include <stdint.h>

typedef unsigned short u16;
typedef __bf16 v8bf __attribute__((ext_vector_type(8)));
typedef float f32x4 __attribute__((ext_vector_type(4)));

#define BATCH 2
#define NSEQ  2048
#define DIM_  2048
#define QH    16
#define KVH   4
#define HD    128
#define KVDIM 512
#define QKVS  3072
#define MROWS (BATCH*NSEQ)

__device__ __forceinline__ u16 f2bf(float f) {
  uint32_t u = __builtin_bit_cast(uint32_t, f);
  u += 0x7FFFu + ((u >> 16) & 1u);
  return (u16)(u >> 16);
}
__device__ __forceinline__ float bf2f(u16 h) {
  uint32_t u = ((uint32_t)h) << 16;
  return __builtin_bit_cast(float, u);
}
__device__ __forceinline__ uint32_t cvt_pk_bf16(float lo, float hi) {
  uint32_t r;
  asm("v_cvt_pk_bf16_f32 %0, %1, %2" : "=v"(r) : "v"(lo), "v"(hi));
  return r;
}
__device__ __forceinline__ void gload_lds16(const void* g, void* l) {
  __builtin_amdgcn_global_load_lds((const __attribute__((address_space(1))) void*)g,
                                   (__attribute__((address_space(3))) void*)l, 16, 0, 0);
}

// ---------------- fused weight converts: Wq|Wk|Wv|Wo -> bf16 ----------------
__global__ void k_conv_w(const float* __restrict__ wq, const float* __restrict__ wk,
                         const float* __restrict__ wv, const float* __restrict__ wo,
                         u16* __restrict__ oq, u16* __restrict__ ok,
                         u16* __restrict__ ov, u16* __restrict__ oo) {
  int i = (blockIdx.x * 256 + threadIdx.x) * 4;
  const float* in; u16* out; int e;
  if (i < 4194304)      { in = wq; out = oq; e = i; }
  else if (i < 5242880) { in = wk; out = ok; e = i - 4194304; }
  else if (i < 6291456) { in = wv; out = ov; e = i - 5242880; }
  else                  { in = wo; out = oo; e = i - 6291456; }
  float4 v = *(const float4*)(in + e);
  ushort4 o;
  o.x = f2bf(v.x); o.y = f2bf(v.y); o.z = f2bf(v.z); o.w = f2bf(v.w);
  *(ushort4*)(out + e) = o;
}

// ---------------- RoPE cos/sin table: [NSEQ][64] float2 ----------------
__global__ void k_rope_table2(float2* __restrict__ tab) {
  int idx = blockIdx.x * 256 + threadIdx.x;
  if (idx < NSEQ * 64) {
    int i = idx & 63;
    float inv = powf(10000.0f, -(float)i / 64.0f);
    float ang = (float)(idx >> 6) * inv;
    tab[idx] = make_float2(cosf(ang), sinf(ang));
  }
}

// ---------------- V transpose ----------------
__global__ void k_transpose_v(const u16* __restrict__ vp, u16* __restrict__ vt) {
  size_t idx = (size_t)blockIdx.x * 256 + threadIdx.x;
  if (idx >= (size_t)BATCH * KVH * HD * NSEQ) return;
  int n = (int)(idx & (NSEQ - 1));
  int d = (int)((idx >> 11) & (HD - 1));
  int h = (int)((idx >> 18) & (KVH - 1));
  int b = (int)(idx >> 20);
  vt[idx] = vp[(size_t)(b * NSEQ + n) * QKVS + h * HD + d];
}

// ---- fused QKV GEMM (2-phase dbuf): A read as fp32 (reg-staged, T14 split), B bf16 via
// ---- global_load_lds. C(4096,3072) bf16 + RoPE fused for Q/K regions.
__global__ __launch_bounds__(256) void k_gemm_qkv(const float* __restrict__ qin, const float* __restrict__ kin,
                                                  const float* __restrict__ vin,
                                                  const u16* __restrict__ wq, const u16* __restrict__ wk,
                                                  const u16* __restrict__ wv,
                                                  const float* __restrict__ bq, const float* __restrict__ bk,
                                                  const float* __restrict__ bv,
                                                  const float2* __restrict__ tab2, u16* __restrict__ C) {
  __shared__ __align__(16) u16 As[2][128 * 32];
  __shared__ __align__(16) u16 Bs[2][128 * 32];
  int tid = threadIdx.x;
  int l = tid & 63, w = tid >> 6;
  int lg = l >> 4, lr = l & 15;
  int wr = w >> 1, wc = w & 1;
  int bm = blockIdx.x, bn = blockIdx.y;

  const float* Af; const u16* B; const float* bias;
  if (bn < 16)      { Af = qin; B = wq + (size_t)(bn * 128) * 2048;        bias = bq + bn * 128; }
  else if (bn < 20) { Af = kin; B = wk + (size_t)((bn - 16) * 128) * 2048; bias = bk + (bn - 16) * 128; }
  else              { Af = vin; B = wv + (size_t)((bn - 20) * 128) * 2048; bias = bv + (bn - 20) * 128; }

  int srow = tid >> 2;          // 0..63
  int scol = (tid & 3) * 16;    // byte offset in 64B row

  const char* Bb = (const char*)B + ((size_t)srow * 2048) * 2 + scol;

  float4 ar0, ar1, ar2, ar3;    // A fp32 in-flight regs (rows srow, srow+64)

#define LOADA(KT)                                                                \
  {                                                                              \
    size_t aoff = (size_t)(bm * 128 + srow) * 2048 + (size_t)(KT) * 32 + (tid & 3) * 8; \
    ar0 = *(const float4*)(Af + aoff);                                           \
    ar1 = *(const float4*)(Af + aoff + 4);                                       \
    ar2 = *(const float4*)(Af + aoff + 131072);                                  \
    ar3 = *(const float4*)(Af + aoff + 131076);                                  \
  }
#define WRITEA(BUF)                                                              \
  {                                                                              \
    uint4 w0, w1;                                                                \
    w0.x = cvt_pk_bf16(ar0.x, ar0.y); w0.y = cvt_pk_bf16(ar0.z, ar0.w);          \
    w0.z = cvt_pk_bf16(ar1.x, ar1.y); w0.w = cvt_pk_bf16(ar1.z, ar1.w);          \
    w1.x = cvt_pk_bf16(ar2.x, ar2.y); w1.y = cvt_pk_bf16(ar2.z, ar2.w);          \
    w1.z = cvt_pk_bf16(ar3.x, ar3.y); w1.w = cvt_pk_bf16(ar3.z, ar3.w);          \
    *(uint4*)((char*)As[BUF] + srow * 64 + scol) = w0;                           \
    *(uint4*)((char*)As[BUF] + (srow + 64) * 64 + scol) = w1;                    \
  }
#define STG_B(BUF, KT)                                                           \
  {                                                                              \
    size_t koff = (size_t)(KT) * 64;                                             \
    gload_lds16(Bb + koff, (char*)Bs[BUF] + srow * 64 + scol);                   \
    gload_lds16(Bb + koff + (size_t)64 * 2048 * 2,                               \
                (char*)Bs[BUF] + (srow + 64) * 64 + scol);                       \
  }

  f32x4 acc[4][4] = {};
  LOADA(0);
  STG_B(0, 0);
  WRITEA(0);
  __syncthreads();
  for (int kt = 0; kt < 64; ++kt) {
    int cur = kt & 1;
    if (kt < 63) { LOADA(kt + 1); STG_B(cur ^ 1, kt + 1); }  // in flight during compute
    const char* AsB = (const char*)As[cur];
    const char* BsB = (const char*)Bs[cur];
    v8bf af[4], bfr[4];
#pragma unroll
    for (int mi = 0; mi < 4; ++mi)
      af[mi] = *(const v8bf*)(AsB + (wr * 64 + mi * 16 + lr) * 64 + lg * 16);
#pragma unroll
    for (int ni = 0; ni < 4; ++ni)
      bfr[ni] = *(const v8bf*)(BsB + (wc * 64 + ni * 16 + lr) * 64 + lg * 16);
#pragma unroll
    for (int mi = 0; mi < 4; ++mi)
#pragma unroll
      for (int ni = 0; ni < 4; ++ni)
        acc[mi][ni] = __builtin_amdgcn_mfma_f32_16x16x32_bf16(af[mi], bfr[ni], acc[mi][ni], 0, 0, 0);
    if (kt < 63) WRITEA(cur ^ 1);   // cvt+ds_write late: A loads had the MFMA phase to land
    __syncthreads();                // drains vmcnt/lgkm: next tile ready, old buffer free
  }
#undef LOADA
#undef WRITEA
#undef STG_B

  bool rope = (bn < 20);
#pragma unroll
  for (int mi = 0; mi < 4; ++mi)
#pragma unroll
    for (int ni = 0; ni < 4; ++ni) {
      int grow0 = bm * 128 + wr * 64 + mi * 16 + lg * 4;
      int lcol = wc * 64 + ni * 16 + lr;
      int gcol = bn * 128 + lcol;
      float bsv = bias[lcol];
      if (rope) {
        int i2 = (gcol & 127) >> 1;
#pragma unroll
        for (int r = 0; r < 4; ++r) {
          float v = acc[mi][ni][r] + bsv;
          float pv = __shfl_xor(v, 1);
          int t = (grow0 + r) & (NSEQ - 1);
          float2 cs = tab2[t * 64 + i2];
          float y = (lr & 1) ? (pv * cs.y + v * cs.x) : (v * cs.x - pv * cs.y);
          C[(size_t)(grow0 + r) * QKVS + gcol] = f2bf(y);
        }
      } else {
#pragma unroll
        for (int r = 0; r < 4; ++r)
          C[(size_t)(grow0 + r) * QKVS + gcol] = f2bf(acc[mi][ni][r] + bsv);
      }
    }
}

// ---------------- bf16 GEMM (2-phase dbuf): C(M,N) = A(M,K) @ B(N,K)^T + bias, fp32 out ----
__global__ __launch_bounds__(256) void k_gemm_bt(const u16* __restrict__ A, const u16* __restrict__ B,
                                                 const float* __restrict__ bias, float* __restrict__ C,
                                                 int M, int N, int K) {
  __shared__ __align__(16) u16 As[2][128 * 32];
  __shared__ __align__(16) u16 Bs[2][128 * 32];
  int tid = threadIdx.x;
  int l = tid & 63, w = tid >> 6;
  int lg = l >> 4, lr = l & 15;
  int wr = w >> 1, wc = w & 1;
  int bm = blockIdx.x, bn = blockIdx.y;

  int srow = tid >> 2;
  int scol = (tid & 3) * 16;

  const char* Ab = (const char*)A + ((size_t)(bm * 128 + srow) * K) * 2 + scol;
  const char* Bb = (const char*)B + ((size_t)(bn * 128 + srow) * K) * 2 + scol;

#define STG(BUF, KT)                                                            \
  {                                                                             \
    size_t koff = (size_t)(KT) * 64;                                            \
    gload_lds16(Ab + koff, (char*)As[BUF] + srow * 64 + scol);                  \
    gload_lds16(Ab + koff + (size_t)64 * K * 2,                                 \
                (char*)As[BUF] + (srow + 64) * 64 + scol);                      \
    gload_lds16(Bb + koff, (char*)Bs[BUF] + srow * 64 + scol);                  \
    gload_lds16(Bb + koff + (size_t)64 * K * 2,                                 \
                (char*)Bs[BUF] + (srow + 64) * 64 + scol);                      \
  }

  f32x4 acc[4][4] = {};
  int ksteps = K >> 5;
  STG(0, 0);
  __syncthreads();
  for (int kt = 0; kt < ksteps; ++kt) {
    int cur = kt & 1;
    if (kt + 1 < ksteps) STG(cur ^ 1, kt + 1);
    const char* AsB = (const char*)As[cur];
    const char* BsB = (const char*)Bs[cur];
    v8bf af[4], bfr[4];
#pragma unroll
    for (int mi = 0; mi < 4; ++mi)
      af[mi] = *(const v8bf*)(AsB + (wr * 64 + mi * 16 + lr) * 64 + lg * 16);
#pragma unroll
    for (int ni = 0; ni < 4; ++ni)
      bfr[ni] = *(const v8bf*)(BsB + (wc * 64 + ni * 16 + lr) * 64 + lg * 16);
#pragma unroll
    for (int mi = 0; mi < 4; ++mi)
#pragma unroll
      for (int ni = 0; ni < 4; ++ni)
        acc[mi][ni] = __builtin_amdgcn_mfma_f32_16x16x32_bf16(af[mi], bfr[ni], acc[mi][ni], 0, 0, 0);
    __syncthreads();
  }
#undef STG

#pragma unroll
  for (int mi = 0; mi < 4; ++mi)
#pragma unroll
    for (int ni = 0; ni < 4; ++ni) {
      int grow0 = bm * 128 + wr * 64 + mi * 16 + lg * 4;
      int gcol = bn * 128 + wc * 64 + ni * 16 + lr;
      float bsv = bias[gcol];
#pragma unroll
      for (int r = 0; r < 4; ++r)
        C[(size_t)(grow0 + r) * N + gcol] = acc[mi][ni][r] + bsv;
    }
}

// ---------------- flash attention v3: swapped QK^T, in-register P (verified) ----------------
__global__ __launch_bounds__(256, 2) void k_attn(const u16* __restrict__ q, const u16* __restrict__ k,
                                                 const u16* __restrict__ vt, u16* __restrict__ out) {
  __shared__ __align__(16) u16 Ks[64 * 128];   // rows=psi(kv), 256B rows, XOR-swizzled
  __shared__ __align__(16) u16 Vs[128 * 64];   // rows=d, 128B rows, XOR-swizzled

  int tid = threadIdx.x;
  int l = tid & 63, w = tid >> 6;
  int lg = l >> 4, lr = l & 15;
  int h = blockIdx.y, b = blockIdx.z;
  int kvh = h >> 2;
  const float SCL2 = 0.12752551286084109f;  // (1/sqrt(128)) * log2(e)
  const float THR2 = 11.541560327111708f;   // 8 * log2(e)

  const char* kbase = (const char*)k + ((size_t)(b * NSEQ) * QKVS + kvh * HD) * 2;
  const char* vbase = (const char*)vt + ((size_t)(b * KVH + kvh) * HD) * NSEQ * 2;
  char* KsB = (char*)Ks;
  char* VsB = (char*)Vs;

  int krow0 = tid >> 4;
  int kcol = (tid & 15) * 16;
  int vrow0 = tid >> 3;
  int vcol = (tid & 7) * 16;

  v8bf kr[4], vr[4];

#define LOADKV(KT)                                                                          \
  {                                                                                         \
    _Pragma("unroll") for (int i = 0; i < 4; ++i)                                           \
        kr[i] = *(const v8bf*)(kbase + (size_t)((KT) * 64 + krow0 + i * 16) * QKVS * 2 + kcol); \
    _Pragma("unroll") for (int i = 0; i < 4; ++i)                                           \
        vr[i] = *(const v8bf*)(vbase + (size_t)(vrow0 + i * 32) * NSEQ * 2 + (size_t)(KT) * 128 + vcol); \
  }
#define WRITEKV()                                                                           \
  {                                                                                         \
    _Pragma("unroll") for (int i = 0; i < 4; ++i) {                                         \
      int kvl = krow0 + i * 16;                                                             \
      int prow = (kvl & 32) + ((kvl & 4) << 2) + ((kvl & 24) >> 1) + (kvl & 3);             \
      *(v8bf*)(KsB + prow * 256 + (kcol ^ ((prow & 7) << 4))) = kr[i];                      \
    }                                                                                       \
    _Pragma("unroll") for (int i = 0; i < 4; ++i) {                                         \
      int row = vrow0 + i * 32;                                                             \
      *(v8bf*)(VsB + row * 128 + (vcol ^ ((row & 7) << 4))) = vr[i];                        \
    }                                                                                       \
  }

  for (int pass = 0; pass < 2; ++pass) {
    int qt = pass ? (31 - blockIdx.x) : blockIdx.x;
    int q0 = qt * 64 + w * 16;

    const char* qb = (const char*)q + ((size_t)(b * NSEQ + q0 + lr) * QKVS + h * HD) * 2;
    v8bf qf[4];
#pragma unroll
    for (int kk = 0; kk < 4; ++kk) qf[kk] = *(const v8bf*)(qb + kk * 64 + lg * 16);

    f32x4 od[8] = {};
    float m2 = -INFINITY, lsum = 0.f;
    int qrow = q0 + lr;

    int ktmax = qt;
    LOADKV(0);
    WRITEKV();
    __syncthreads();

    for (int kt = 0; kt <= ktmax; ++kt) {
      if (kt < ktmax) LOADKV(kt + 1);

      f32x4 st[4];
      __builtin_amdgcn_s_setprio(1);
#pragma unroll
      for (int nt = 0; nt < 4; ++nt) {
        f32x4 a = {};
#pragma unroll
        for (int kk = 0; kk < 4; ++kk) {
          int krow = nt * 16 + lr;
          v8bf kf = *(const v8bf*)(KsB + krow * 256 + ((kk * 64 + lg * 16) ^ ((krow & 7) << 4)));
          a = __builtin_amdgcn_mfma_f32_16x16x32_bf16(kf, qf[kk], a, 0, 0, 0);
        }
        st[nt] = a;
      }
      __builtin_amdgcn_s_setprio(0);

      float mx = -1e30f;
#pragma unroll
      for (int nt = 0; nt < 4; ++nt)
#pragma unroll
        for (int r = 0; r < 4; ++r) {
          int kv = kt * 64 + (nt >> 1) * 32 + lg * 8 + ((nt & 1) << 2) + r;
          float v = st[nt][r] * SCL2;
          if (kv > qrow) v = -1e30f;
          st[nt][r] = v;
          mx = fmaxf(mx, v);
        }
      mx = fmaxf(mx, __shfl_xor(mx, 16));
      mx = fmaxf(mx, __shfl_xor(mx, 32));

      if (!__all(mx - m2 <= THR2)) {
        float nm2 = fmaxf(m2, mx);
        float corrf = exp2f(m2 - nm2);
        m2 = nm2;
        lsum *= corrf;
#pragma unroll
        for (int r = 0; r < 4; ++r) {
          float cb = __shfl(corrf, lg * 4 + r);
#pragma unroll
          for (int dt = 0; dt < 8; ++dt) od[dt][r] *= cb;
        }
      }

      float rs = 0.f;
#pragma unroll
      for (int nt = 0; nt < 4; ++nt)
#pragma unroll
        for (int r = 0; r < 4; ++r) {
          float pv = exp2f(st[nt][r] - m2);
          st[nt][r] = pv;
          rs += pv;
        }
      rs += __shfl_xor(rs, 16);
      rs += __shfl_xor(rs, 32);
      lsum += rs;

      uint32_t pk[4][2];
#pragma unroll
      for (int nt = 0; nt < 4; ++nt)
#pragma unroll
        for (int s = 0; s < 2; ++s)
          pk[nt][s] = cvt_pk_bf16(st[nt][2 * s], st[nt][2 * s + 1]);

      __builtin_amdgcn_s_setprio(1);
#pragma unroll
      for (int kc = 0; kc < 2; ++kc) {
        union { uint32_t u[4]; v8bf v; } pfu;
        pfu.u[0] = pk[2 * kc][0];
        pfu.u[1] = pk[2 * kc][1];
        pfu.u[2] = pk[2 * kc + 1][0];
        pfu.u[3] = pk[2 * kc + 1][1];
#pragma unroll
        for (int dt = 0; dt < 8; ++dt) {
          int vrow = dt * 16 + lr;
          v8bf vf = *(const v8bf*)(VsB + vrow * 128 + ((kc * 64 + lg * 16) ^ ((vrow & 7) << 4)));
          od[dt] = __builtin_amdgcn_mfma_f32_16x16x32_bf16(pfu.v, vf, od[dt], 0, 0, 0);
        }
      }
      __builtin_amdgcn_s_setprio(0);

      __syncthreads();
      if (kt < ktmax) WRITEKV();
      __syncthreads();
    }

#pragma unroll
    for (int r = 0; r < 4; ++r) {
      float ls = __shfl(lsum, lg * 4 + r);
      float inv = 1.0f / ls;
      int qr = q0 + lg * 4 + r;
      char* ob = (char*)out + ((size_t)(b * NSEQ + qr) * DIM_ + h * HD) * 2;
#pragma unroll
      for (int dt = 0; dt < 8; ++dt)
        *(u16*)(ob + (dt * 16 + lr) * 2) = f2bf(od[dt][r] * inv);
    }
  }
#undef LOADKV
#undef WRITEKV
}

// ---------------- launch ----------------
extern "C" void kernel_launch(void* const* d_in, const int* in_sizes, int n_in,
                              void* d_out, int out_size, void* d_ws, size_t ws_size,
                              hipStream_t stream) {
  const float* query = (const float*)d_in[0];
  const float* key_ = (const float*)d_in[1];
  const float* value = (const float*)d_in[2];
  const float* Wq = (const float*)d_in[3];
  const float* bq = (const float*)d_in[4];
  const float* Wk = (const float*)d_in[5];
  const float* bk = (const float*)d_in[6];
  const float* Wv = (const float*)d_in[7];
  const float* bv = (const float*)d_in[8];
  const float* Wo = (const float*)d_in[9];
  const float* bo = (const float*)d_in[10];

  char* ws = (char*)d_ws;
  u16* wq_bf = (u16*)(ws + 0);
  u16* wk_bf = (u16*)(ws + 8388608);
  u16* wv_bf = (u16*)(ws + 10485760);
  u16* wo_bf = (u16*)(ws + 12582912);
  float2* tab2 = (float2*)(ws + 20971520);
  u16* vt = (u16*)(ws + 22020096);      // 16,777,216 (ex-xq)
  u16* attno = (u16*)(ws + 38797312);   // 16,777,216 (ex-xk)
  u16* qkvproj = (u16*)(ws + 72351744); // 25,165,824

  k_conv_w<<<dim3(10240), 256, 0, stream>>>(Wq, Wk, Wv, Wo, wq_bf, wk_bf, wv_bf, wo_bf);
  k_rope_table2<<<dim3(NSEQ * 64 / 256), 256, 0, stream>>>(tab2);

  k_gemm_qkv<<<dim3(MROWS / 128, QKVS / 128), 256, 0, stream>>>(query, key_, value,
                                                                wq_bf, wk_bf, wv_bf,
                                                                bq, bk, bv, tab2, qkvproj);

  k_transpose_v<<<dim3((BATCH * KVH * HD * NSEQ) / 256), 256, 0, stream>>>(qkvproj + 2560, vt);

  k_attn<<<dim3(NSEQ / 128, QH, BATCH), 256, 0, stream>>>(qkvproj, qkvproj + 2048, vt, attno);

  k_gemm_bt<<<dim3(MROWS / 128, DIM_ / 128), 256, 0, stream>>>(attno, wo_bf, bo, (float*)d_out, MROWS, DIM_, DIM_);
}

// Round 9
// 223.304 us; speedup vs baseline: 1.3024x; 1.0196x over previous
//
#include <hip/hip_runtime.h>
#include <hip/hip_bf16.h>
#include <stdint.h>

typedef unsigned short u16;
typedef __bf16 v8bf __attribute__((ext_vector_type(8)));
typedef float f32x4 __attribute__((ext_vector_type(4)));

#define BATCH 2
#define NSEQ  2048
#define DIM_  2048
#define QH    16
#define KVH   4
#define HD    128
#define KVDIM 512
#define QKVS  3072
#define MROWS (BATCH*NSEQ)

__device__ __forceinline__ u16 f2bf(float f) {
  uint32_t u = __builtin_bit_cast(uint32_t, f);
  u += 0x7FFFu + ((u >> 16) & 1u);
  return (u16)(u >> 16);
}
__device__ __forceinline__ float bf2f(u16 h) {
  uint32_t u = ((uint32_t)h) << 16;
  return __builtin_bit_cast(float, u);
}
__device__ __forceinline__ uint32_t cvt_pk_bf16(float lo, float hi) {
  uint32_t r;
  asm("v_cvt_pk_bf16_f32 %0, %1, %2" : "=v"(r) : "v"(lo), "v"(hi));
  return r;
}
__device__ __forceinline__ void gload_lds16(const void* g, void* l) {
  __builtin_amdgcn_global_load_lds((const __attribute__((address_space(1))) void*)g,
                                   (__attribute__((address_space(3))) void*)l, 16, 0, 0);
}

// ---------------- fused weight converts: Wq|Wk|Wv|Wo -> bf16 ----------------
__global__ void k_conv_w(const float* __restrict__ wq, const float* __restrict__ wk,
                         const float* __restrict__ wv, const float* __restrict__ wo,
                         u16* __restrict__ oq, u16* __restrict__ ok,
                         u16* __restrict__ ov, u16* __restrict__ oo) {
  int i = (blockIdx.x * 256 + threadIdx.x) * 4;
  const float* in; u16* out; int e;
  if (i < 4194304)      { in = wq; out = oq; e = i; }
  else if (i < 5242880) { in = wk; out = ok; e = i - 4194304; }
  else if (i < 6291456) { in = wv; out = ov; e = i - 5242880; }
  else                  { in = wo; out = oo; e = i - 6291456; }
  float4 v = *(const float4*)(in + e);
  ushort4 o;
  o.x = f2bf(v.x); o.y = f2bf(v.y); o.z = f2bf(v.z); o.w = f2bf(v.w);
  *(ushort4*)(out + e) = o;
}

// ---------------- RoPE cos/sin table: [NSEQ][64] float2 ----------------
__global__ void k_rope_table2(float2* __restrict__ tab) {
  int idx = blockIdx.x * 256 + threadIdx.x;
  if (idx < NSEQ * 64) {
    int i = idx & 63;
    float inv = powf(10000.0f, -(float)i / 64.0f);
    float ang = (float)(idx >> 6) * inv;
    tab[idx] = make_float2(cosf(ang), sinf(ang));
  }
}

// ------- V transpose, LDS-tiled 64x64 (coalesced reads AND writes) -------
// vp = qkvproj V region: rows (MROWS, stride QKVS), cols 0..511 (= kvh*128+d).
// vt: (B, KVH, 128, NSEQ). grid (MROWS/64, 512/64) = (64, 8), 256 threads.
__global__ __launch_bounds__(256) void k_transpose_v(const u16* __restrict__ vp, u16* __restrict__ vt) {
  __shared__ u16 t[64][72];   // [n][d], pad 64->72
  int bn = blockIdx.x, bd = blockIdx.y;
  int tid = threadIdx.x;
  int rrow = tid >> 3;            // 0..31
  int rcol = (tid & 7) * 8;       // 0..56
#pragma unroll
  for (int i = 0; i < 2; ++i) {
    int n = rrow + i * 32;
    ushort4 v0 = *(const ushort4*)(vp + (size_t)(bn * 64 + n) * QKVS + bd * 64 + rcol);
    ushort4 v1 = *(const ushort4*)(vp + (size_t)(bn * 64 + n) * QKVS + bd * 64 + rcol + 4);
    *(ushort4*)&t[n][rcol] = v0;
    *(ushort4*)&t[n][rcol + 4] = v1;
  }
  __syncthreads();
  int b = bn >> 5;                // 2048 rows per batch / 64 = 32 tiles
  int nbase = (bn & 31) * 64;
#pragma unroll
  for (int i = 0; i < 2; ++i) {
    int dl = rrow + i * 32;       // 0..63 within this d-tile
    int dglob = bd * 64 + dl;     // 0..511
    int kvh = dglob >> 7, dd = dglob & 127;
    ushort4 o0, o1;
    o0.x = t[rcol + 0][dl]; o0.y = t[rcol + 1][dl];
    o0.z = t[rcol + 2][dl]; o0.w = t[rcol + 3][dl];
    o1.x = t[rcol + 4][dl]; o1.y = t[rcol + 5][dl];
    o1.z = t[rcol + 6][dl]; o1.w = t[rcol + 7][dl];
    u16* dst = vt + (((size_t)(b * KVH + kvh) * HD + dd) * NSEQ + nbase + rcol);
    *(ushort4*)dst = o0;
    *(ushort4*)(dst + 4) = o1;
  }
}

// ---- fused QKV GEMM (2-phase dbuf): A read as fp32 (reg-staged, T14 split), B bf16 via
// ---- global_load_lds. C(4096,3072) bf16 + RoPE fused for Q/K regions. (unchanged r8)
__global__ __launch_bounds__(256) void k_gemm_qkv(const float* __restrict__ qin, const float* __restrict__ kin,
                                                  const float* __restrict__ vin,
                                                  const u16* __restrict__ wq, const u16* __restrict__ wk,
                                                  const u16* __restrict__ wv,
                                                  const float* __restrict__ bq, const float* __restrict__ bk,
                                                  const float* __restrict__ bv,
                                                  const float2* __restrict__ tab2, u16* __restrict__ C) {
  __shared__ __align__(16) u16 As[2][128 * 32];
  __shared__ __align__(16) u16 Bs[2][128 * 32];
  int tid = threadIdx.x;
  int l = tid & 63, w = tid >> 6;
  int lg = l >> 4, lr = l & 15;
  int wr = w >> 1, wc = w & 1;
  int bm = blockIdx.x, bn = blockIdx.y;

  const float* Af; const u16* B; const float* bias;
  if (bn < 16)      { Af = qin; B = wq + (size_t)(bn * 128) * 2048;        bias = bq + bn * 128; }
  else if (bn < 20) { Af = kin; B = wk + (size_t)((bn - 16) * 128) * 2048; bias = bk + (bn - 16) * 128; }
  else              { Af = vin; B = wv + (size_t)((bn - 20) * 128) * 2048; bias = bv + (bn - 20) * 128; }

  int srow = tid >> 2;
  int scol = (tid & 3) * 16;

  const char* Bb = (const char*)B + ((size_t)srow * 2048) * 2 + scol;

  float4 ar0, ar1, ar2, ar3;

#define LOADA(KT)                                                                \
  {                                                                              \
    size_t aoff = (size_t)(bm * 128 + srow) * 2048 + (size_t)(KT) * 32 + (tid & 3) * 8; \
    ar0 = *(const float4*)(Af + aoff);                                           \
    ar1 = *(const float4*)(Af + aoff + 4);                                       \
    ar2 = *(const float4*)(Af + aoff + 131072);                                  \
    ar3 = *(const float4*)(Af + aoff + 131076);                                  \
  }
#define WRITEA(BUF)                                                              \
  {                                                                              \
    uint4 w0, w1;                                                                \
    w0.x = cvt_pk_bf16(ar0.x, ar0.y); w0.y = cvt_pk_bf16(ar0.z, ar0.w);          \
    w0.z = cvt_pk_bf16(ar1.x, ar1.y); w0.w = cvt_pk_bf16(ar1.z, ar1.w);          \
    w1.x = cvt_pk_bf16(ar2.x, ar2.y); w1.y = cvt_pk_bf16(ar2.z, ar2.w);          \
    w1.z = cvt_pk_bf16(ar3.x, ar3.y); w1.w = cvt_pk_bf16(ar3.z, ar3.w);          \
    *(uint4*)((char*)As[BUF] + srow * 64 + scol) = w0;                           \
    *(uint4*)((char*)As[BUF] + (srow + 64) * 64 + scol) = w1;                    \
  }
#define STG_B(BUF, KT)                                                           \
  {                                                                              \
    size_t koff = (size_t)(KT) * 64;                                             \
    gload_lds16(Bb + koff, (char*)Bs[BUF] + srow * 64 + scol);                   \
    gload_lds16(Bb + koff + (size_t)64 * 2048 * 2,                               \
                (char*)Bs[BUF] + (srow + 64) * 64 + scol);                       \
  }

  f32x4 acc[4][4] = {};
  LOADA(0);
  STG_B(0, 0);
  WRITEA(0);
  __syncthreads();
  for (int kt = 0; kt < 64; ++kt) {
    int cur = kt & 1;
    if (kt < 63) { LOADA(kt + 1); STG_B(cur ^ 1, kt + 1); }
    const char* AsB = (const char*)As[cur];
    const char* BsB = (const char*)Bs[cur];
    v8bf af[4], bfr[4];
#pragma unroll
    for (int mi = 0; mi < 4; ++mi)
      af[mi] = *(const v8bf*)(AsB + (wr * 64 + mi * 16 + lr) * 64 + lg * 16);
#pragma unroll
    for (int ni = 0; ni < 4; ++ni)
      bfr[ni] = *(const v8bf*)(BsB + (wc * 64 + ni * 16 + lr) * 64 + lg * 16);
#pragma unroll
    for (int mi = 0; mi < 4; ++mi)
#pragma unroll
      for (int ni = 0; ni < 4; ++ni)
        acc[mi][ni] = __builtin_amdgcn_mfma_f32_16x16x32_bf16(af[mi], bfr[ni], acc[mi][ni], 0, 0, 0);
    if (kt < 63) WRITEA(cur ^ 1);
    __syncthreads();
  }
#undef LOADA
#undef WRITEA
#undef STG_B

  bool rope = (bn < 20);
#pragma unroll
  for (int mi = 0; mi < 4; ++mi)
#pragma unroll
    for (int ni = 0; ni < 4; ++ni) {
      int grow0 = bm * 128 + wr * 64 + mi * 16 + lg * 4;
      int lcol = wc * 64 + ni * 16 + lr;
      int gcol = bn * 128 + lcol;
      float bsv = bias[lcol];
      if (rope) {
        int i2 = (gcol & 127) >> 1;
#pragma unroll
        for (int r = 0; r < 4; ++r) {
          float v = acc[mi][ni][r] + bsv;
          float pv = __shfl_xor(v, 1);
          int t = (grow0 + r) & (NSEQ - 1);
          float2 cs = tab2[t * 64 + i2];
          float y = (lr & 1) ? (pv * cs.y + v * cs.x) : (v * cs.x - pv * cs.y);
          C[(size_t)(grow0 + r) * QKVS + gcol] = f2bf(y);
        }
      } else {
#pragma unroll
        for (int r = 0; r < 4; ++r)
          C[(size_t)(grow0 + r) * QKVS + gcol] = f2bf(acc[mi][ni][r] + bsv);
      }
    }
}

// ---------------- bf16 GEMM (2-phase dbuf): fp32 out (unchanged r8) ----------------
__global__ __launch_bounds__(256) void k_gemm_bt(const u16* __restrict__ A, const u16* __restrict__ B,
                                                 const float* __restrict__ bias, float* __restrict__ C,
                                                 int M, int N, int K) {
  __shared__ __align__(16) u16 As[2][128 * 32];
  __shared__ __align__(16) u16 Bs[2][128 * 32];
  int tid = threadIdx.x;
  int l = tid & 63, w = tid >> 6;
  int lg = l >> 4, lr = l & 15;
  int wr = w >> 1, wc = w & 1;
  int bm = blockIdx.x, bn = blockIdx.y;

  int srow = tid >> 2;
  int scol = (tid & 3) * 16;

  const char* Ab = (const char*)A + ((size_t)(bm * 128 + srow) * K) * 2 + scol;
  const char* Bb = (const char*)B + ((size_t)(bn * 128 + srow) * K) * 2 + scol;

#define STG(BUF, KT)                                                            \
  {                                                                             \
    size_t koff = (size_t)(KT) * 64;                                            \
    gload_lds16(Ab + koff, (char*)As[BUF] + srow * 64 + scol);                  \
    gload_lds16(Ab + koff + (size_t)64 * K * 2,                                 \
                (char*)As[BUF] + (srow + 64) * 64 + scol);                      \
    gload_lds16(Bb + koff, (char*)Bs[BUF] + srow * 64 + scol);                  \
    gload_lds16(Bb + koff + (size_t)64 * K * 2,                                 \
                (char*)Bs[BUF] + (srow + 64) * 64 + scol);                      \
  }

  f32x4 acc[4][4] = {};
  int ksteps = K >> 5;
  STG(0, 0);
  __syncthreads();
  for (int kt = 0; kt < ksteps; ++kt) {
    int cur = kt & 1;
    if (kt + 1 < ksteps) STG(cur ^ 1, kt + 1);
    const char* AsB = (const char*)As[cur];
    const char* BsB = (const char*)Bs[cur];
    v8bf af[4], bfr[4];
#pragma unroll
    for (int mi = 0; mi < 4; ++mi)
      af[mi] = *(const v8bf*)(AsB + (wr * 64 + mi * 16 + lr) * 64 + lg * 16);
#pragma unroll
    for (int ni = 0; ni < 4; ++ni)
      bfr[ni] = *(const v8bf*)(BsB + (wc * 64 + ni * 16 + lr) * 64 + lg * 16);
#pragma unroll
    for (int mi = 0; mi < 4; ++mi)
#pragma unroll
      for (int ni = 0; ni < 4; ++ni)
        acc[mi][ni] = __builtin_amdgcn_mfma_f32_16x16x32_bf16(af[mi], bfr[ni], acc[mi][ni], 0, 0, 0);
    __syncthreads();
  }
#undef STG

#pragma unroll
  for (int mi = 0; mi < 4; ++mi)
#pragma unroll
    for (int ni = 0; ni < 4; ++ni) {
      int grow0 = bm * 128 + wr * 64 + mi * 16 + lg * 4;
      int gcol = bn * 128 + wc * 64 + ni * 16 + lr;
      float bsv = bias[gcol];
#pragma unroll
      for (int r = 0; r < 4; ++r)
        C[(size_t)(grow0 + r) * N + gcol] = acc[mi][ni][r] + bsv;
    }
}

// ---------------- flash attention v4: 8 waves, 128-row q-tiles ----------------
// Per-wave algebra identical to v3 (16 q-rows/wave, swapped QK^T, psi-permuted K, in-reg P).
// Block: 512 thr = 8 waves covering 128 q-rows; pairs (j, 15-j) -> uniform 34 kv-iters;
// staging per tile shared by 8 waves (half the traffic of v3). grid (8, QH, BATCH).
__global__ __launch_bounds__(512, 2) void k_attn(const u16* __restrict__ q, const u16* __restrict__ k,
                                                 const u16* __restrict__ vt, u16* __restrict__ out) {
  __shared__ __align__(16) u16 Ks[64 * 128];   // rows=psi(kv), 256B rows, XOR-swizzled
  __shared__ __align__(16) u16 Vs[128 * 64];   // rows=d, 128B rows, XOR-swizzled

  int tid = threadIdx.x;
  int l = tid & 63, w = tid >> 6;              // w: 0..7
  int lg = l >> 4, lr = l & 15;
  int h = blockIdx.y, b = blockIdx.z;
  int kvh = h >> 2;
  const float SCL2 = 0.12752551286084109f;  // (1/sqrt(128)) * log2(e)
  const float THR2 = 11.541560327111708f;   // 8 * log2(e)

  const char* kbase = (const char*)k + ((size_t)(b * NSEQ) * QKVS + kvh * HD) * 2;
  const char* vbase = (const char*)vt + ((size_t)(b * KVH + kvh) * HD) * NSEQ * 2;
  char* KsB = (char*)Ks;
  char* VsB = (char*)Vs;

  int krow0 = tid >> 4;          // 0..31 (x2 rows via i)
  int kcol = (tid & 15) * 16;    // 0..240
  int vrow0 = tid >> 3;          // 0..63 (x2 rows via i)
  int vcol = (tid & 7) * 16;     // 0..112

  v8bf kr[2], vr[2];

#define LOADKV(KT)                                                                          \
  {                                                                                         \
    _Pragma("unroll") for (int i = 0; i < 2; ++i)                                           \
        kr[i] = *(const v8bf*)(kbase + (size_t)((KT) * 64 + krow0 + i * 32) * QKVS * 2 + kcol); \
    _Pragma("unroll") for (int i = 0; i < 2; ++i)                                           \
        vr[i] = *(const v8bf*)(vbase + (size_t)(vrow0 + i * 64) * NSEQ * 2 + (size_t)(KT) * 128 + vcol); \
  }
#define WRITEKV()                                                                           \
  {                                                                                         \
    _Pragma("unroll") for (int i = 0; i < 2; ++i) {                                         \
      int kvl = krow0 + i * 32;                                                             \
      int prow = (kvl & 32) + ((kvl & 4) << 2) + ((kvl & 24) >> 1) + (kvl & 3);             \
      *(v8bf*)(KsB + prow * 256 + (kcol ^ ((prow & 7) << 4))) = kr[i];                      \
    }                                                                                       \
    _Pragma("unroll") for (int i = 0; i < 2; ++i) {                                         \
      int row = vrow0 + i * 64;                                                             \
      *(v8bf*)(VsB + row * 128 + (vcol ^ ((row & 7) << 4))) = vr[i];                        \
    }                                                                                       \
  }

  for (int pass = 0; pass < 2; ++pass) {
    int qt = pass ? (15 - blockIdx.x) : blockIdx.x;    // 128-row q-tile index
    int q0 = qt * 128 + w * 16;

    const char* qb = (const char*)q + ((size_t)(b * NSEQ + q0 + lr) * QKVS + h * HD) * 2;
    v8bf qf[4];
#pragma unroll
    for (int kk = 0; kk < 4; ++kk) qf[kk] = *(const v8bf*)(qb + kk * 64 + lg * 16);

    f32x4 od[8] = {};
    float m2 = -INFINITY, lsum = 0.f;
    int qrow = q0 + lr;

    int ktmax = 2 * qt + 1;        // kv tiles (64-wide) up to the diagonal
    LOADKV(0);
    WRITEKV();
    __syncthreads();

    for (int kt = 0; kt <= ktmax; ++kt) {
      if (kt < ktmax) LOADKV(kt + 1);

      f32x4 st[4];
      __builtin_amdgcn_s_setprio(1);
#pragma unroll
      for (int nt = 0; nt < 4; ++nt) {
        f32x4 a = {};
#pragma unroll
        for (int kk = 0; kk < 4; ++kk) {
          int krow = nt * 16 + lr;
          v8bf kf = *(const v8bf*)(KsB + krow * 256 + ((kk * 64 + lg * 16) ^ ((krow & 7) << 4)));
          a = __builtin_amdgcn_mfma_f32_16x16x32_bf16(kf, qf[kk], a, 0, 0, 0);
        }
        st[nt] = a;
      }
      __builtin_amdgcn_s_setprio(0);

      float mx = -1e30f;
#pragma unroll
      for (int nt = 0; nt < 4; ++nt)
#pragma unroll
        for (int r = 0; r < 4; ++r) {
          int kv = kt * 64 + (nt >> 1) * 32 + lg * 8 + ((nt & 1) << 2) + r;
          float v = st[nt][r] * SCL2;
          if (kv > qrow) v = -1e30f;
          st[nt][r] = v;
          mx = fmaxf(mx, v);
        }
      mx = fmaxf(mx, __shfl_xor(mx, 16));
      mx = fmaxf(mx, __shfl_xor(mx, 32));

      if (!__all(mx - m2 <= THR2)) {
        float nm2 = fmaxf(m2, mx);
        float corrf = exp2f(m2 - nm2);
        m2 = nm2;
        lsum *= corrf;
#pragma unroll
        for (int r = 0; r < 4; ++r) {
          float cb = __shfl(corrf, lg * 4 + r);
#pragma unroll
          for (int dt = 0; dt < 8; ++dt) od[dt][r] *= cb;
        }
      }

      float rs = 0.f;
#pragma unroll
      for (int nt = 0; nt < 4; ++nt)
#pragma unroll
        for (int r = 0; r < 4; ++r) {
          float pv = exp2f(st[nt][r] - m2);
          st[nt][r] = pv;
          rs += pv;
        }
      rs += __shfl_xor(rs, 16);
      rs += __shfl_xor(rs, 32);
      lsum += rs;

      uint32_t pk[4][2];
#pragma unroll
      for (int nt = 0; nt < 4; ++nt)
#pragma unroll
        for (int s = 0; s < 2; ++s)
          pk[nt][s] = cvt_pk_bf16(st[nt][2 * s], st[nt][2 * s + 1]);

      __builtin_amdgcn_s_setprio(1);
#pragma unroll
      for (int kc = 0; kc < 2; ++kc) {
        union { uint32_t u[4]; v8bf v; } pfu;
        pfu.u[0] = pk[2 * kc][0];
        pfu.u[1] = pk[2 * kc][1];
        pfu.u[2] = pk[2 * kc + 1][0];
        pfu.u[3] = pk[2 * kc + 1][1];
#pragma unroll
        for (int dt = 0; dt < 8; ++dt) {
          int vrow = dt * 16 + lr;
          v8bf vf = *(const v8bf*)(VsB + vrow * 128 + ((kc * 64 + lg * 16) ^ ((vrow & 7) << 4)));
          od[dt] = __builtin_amdgcn_mfma_f32_16x16x32_bf16(pfu.v, vf, od[dt], 0, 0, 0);
        }
      }
      __builtin_amdgcn_s_setprio(0);

      __syncthreads();
      if (kt < ktmax) WRITEKV();
      __syncthreads();
    }

#pragma unroll
    for (int r = 0; r < 4; ++r) {
      float ls = __shfl(lsum, lg * 4 + r);
      float inv = 1.0f / ls;
      int qr = q0 + lg * 4 + r;
      char* ob = (char*)out + ((size_t)(b * NSEQ + qr) * DIM_ + h * HD) * 2;
#pragma unroll
      for (int dt = 0; dt < 8; ++dt)
        *(u16*)(ob + (dt * 16 + lr) * 2) = f2bf(od[dt][r] * inv);
    }
  }
#undef LOADKV
#undef WRITEKV
}

// ---------------- launch ----------------
extern "C" void kernel_launch(void* const* d_in, const int* in_sizes, int n_in,
                              void* d_out, int out_size, void* d_ws, size_t ws_size,
                              hipStream_t stream) {
  const float* query = (const float*)d_in[0];
  const float* key_ = (const float*)d_in[1];
  const float* value = (const float*)d_in[2];
  const float* Wq = (const float*)d_in[3];
  const float* bq = (const float*)d_in[4];
  const float* Wk = (const float*)d_in[5];
  const float* bk = (const float*)d_in[6];
  const float* Wv = (const float*)d_in[7];
  const float* bv = (const float*)d_in[8];
  const float* Wo = (const float*)d_in[9];
  const float* bo = (const float*)d_in[10];

  char* ws = (char*)d_ws;
  u16* wq_bf = (u16*)(ws + 0);
  u16* wk_bf = (u16*)(ws + 8388608);
  u16* wv_bf = (u16*)(ws + 10485760);
  u16* wo_bf = (u16*)(ws + 12582912);
  float2* tab2 = (float2*)(ws + 20971520);
  u16* vt = (u16*)(ws + 22020096);      // 16,777,216
  u16* attno = (u16*)(ws + 38797312);   // 16,777,216
  u16* qkvproj = (u16*)(ws + 72351744); // 25,165,824

  k_conv_w<<<dim3(10240), 256, 0, stream>>>(Wq, Wk, Wv, Wo, wq_bf, wk_bf, wv_bf, wo_bf);
  k_rope_table2<<<dim3(NSEQ * 64 / 256), 256, 0, stream>>>(tab2);

  k_gemm_qkv<<<dim3(MROWS / 128, QKVS / 128), 256, 0, stream>>>(query, key_, value,
                                                                wq_bf, wk_bf, wv_bf,
                                                                bq, bk, bv, tab2, qkvproj);

  k_transpose_v<<<dim3(MROWS / 64, KVDIM / 64), 256, 0, stream>>>(qkvproj + 2560, vt);

  k_attn<<<dim3(8, QH, BATCH), 512, 0, stream>>>(qkvproj, qkvproj + 2048, vt, attno);

  k_gemm_bt<<<dim3(MROWS / 128, DIM_ / 128), 256, 0, stream>>>(attno, wo_bf, bo, (float*)d_out, MROWS, DIM_, DIM_);
}